// Round 6
// baseline (208.775 us; speedup 1.0000x reference)
//
#include <hip/hip_runtime.h>
#include <hip/hip_bf16.h>

typedef __attribute__((ext_vector_type(4))) float f32x4;
typedef __attribute__((ext_vector_type(8))) __bf16 bf16x8;
typedef __attribute__((ext_vector_type(4))) unsigned int uint4v;

constexpr int M = 16384;
constexpr int N = 1024;
constexpr int K = 2048;
constexpr int BM = 256, BN = 256;  // block tile
constexpr int NT = K / 32;         // 64 windows of BK=32
constexpr float BN_EPS = 1e-5f;
constexpr int TM2 = M / BM;  // 64 row-tiles (psum partials)

// async 16B global -> LDS (lds dest must be wave-uniform; HW adds lane*16)
#define GLOAD_LDS16(g, l)                                                      \
  __builtin_amdgcn_global_load_lds(                                            \
      (const __attribute__((address_space(1))) void*)(g),                      \
      (__attribute__((address_space(3))) void*)(l), 16, 0, 0)

#define SB0 __builtin_amdgcn_sched_barrier(0)
#define BARRIER __builtin_amdgcn_s_barrier()
#define VMC(n) asm volatile("s_waitcnt vmcnt(" #n ")" ::: "memory")
#define LGKM0 asm volatile("s_waitcnt lgkmcnt(0)" ::: "memory")

__device__ __forceinline__ unsigned sgnbf(float f) {
  return (f >= 0.f) ? 0x3F80u : 0xBF80u;
}
__global__ __launch_bounds__(256) void binw_kernel(
    const float* __restrict__ w, uint4v* __restrict__ wb) {
  size_t i = (size_t)blockIdx.x * 256 + threadIdx.x;
  const f32x4* win = (const f32x4*)w;
  f32x4 v0 = win[i * 2];
  f32x4 v1 = win[i * 2 + 1];
  uint4v o;
  o.x = sgnbf(v0[0]) | (sgnbf(v0[1]) << 16);
  o.y = sgnbf(v0[2]) | (sgnbf(v0[3]) << 16);
  o.z = sgnbf(v1[0]) | (sgnbf(v1[1]) << 16);
  o.w = sgnbf(v1[2]) | (sgnbf(v1[3]) << 16);
  wb[i] = o;
}

// ---- bf16 GEMM: 256^2 tile, 8 waves (4M x 2N), wave tile 64x128 ----
// LDS-bandwidth-balanced design: per CU per BK=32 window the LDS port sees
// only 64 ds_read_b128 (8/wave, B only, 0.25 reads/MFMA) + 16KB of gload
// DMA writes (~960 cyc) vs 1242 cyc of matrix-pipe work -> MFMA is the
// binding pipe (prior rounds: 128 reads/window = ~1540 cyc = the wall).
// A (x fp32) never touches LDS: each lane loads its 4 MFMA A-fragments
// global->reg (4 lanes per 128B line, fully coalesced; L2/LLC absorbs the
// 8x panel reuse - FETCH_SIZE stayed ~82MB in all rounds), cvt at window
// end, 1 window deep. B staged via gload_lds (pre-swizzled source, R4-
// verified 0-conflict layout) into 2-slot LDS. One barrier + one vmcnt(0)
// (of ~window-old loads) per window.
__global__ __launch_bounds__(512, 2) void gemm_bin_kernel(
    const float* __restrict__ Af, const unsigned short* __restrict__ B,
    float* __restrict__ Y, float* __restrict__ psum, float* __restrict__ psq) {
  __shared__ unsigned short Bs[2][8192];  // 32 KiB: [slot][row*32 + chunk*8]
  __shared__ float redsum[4][256];        // 4 KiB
  __shared__ float redsq[4][256];         // 4 KiB

  const int tid = threadIdx.x;
  const int wid = tid >> 6;
  const int lane = tid & 63;
  const int wr = wid >> 1, wc = wid & 1;  // 4M x 2N wave grid

  // T1: XCD swizzle (grid 256, %8==0): XCD owns contiguous tm range.
  const int bid = blockIdx.x;
  const int swz = (bid & 7) * 32 + (bid >> 3);
  const int tm = swz >> 2, tn = swz & 3;
  const size_t m0 = (size_t)tm * BM, n0 = (size_t)tn * BN;

  const int frow = lane & 15;  // fragment row/col within 16x16
  const int fcb = lane >> 4;   // k chunk 0..3
  const int swq = (frow >> 1) & 3;

  // B frag read (ushort idx): row = wc*128 + nj*16 + frow (nj via +512),
  // chunk = fcb ^ swq (involution; R4-measured 0 conflicts on this layout)
  const int boff = (wc * 128 + frow) * 32 + (fcb ^ swq) * 8;

  // B staging: wave stages LDS rows [wid*32, +32) = 2 gloads x 16 rows.
  // lane: row += lane>>2, lds chunk = lane&3, glob chunk = (lane&3)^((lane>>3)&3)
  const int bgc = (lane & 3) ^ ((lane >> 3) & 3);
  const unsigned short* pBg =
      B + (n0 + wid * 32 + (lane >> 2)) * (size_t)K + bgc * 8;

  // A: lane's 4 frag rows = m0 + wr*64 + mi*16 + frow, k-bytes [fcb*32,+32)
  const float* pA = Af + (m0 + wr * 64 + frow) * (size_t)K + fcb * 8;

  f32x4 acc[4][8];
#pragma unroll
  for (int mi = 0; mi < 4; ++mi)
#pragma unroll
    for (int nj = 0; nj < 8; ++nj)
#pragma unroll
      for (int j = 0; j < 4; ++j) acc[mi][nj][j] = 0.f;

  // A staging regs (1 window deep) + converted fragments
  f32x4 xr0, xr1, xr2, xr3, xr4, xr5, xr6, xr7;
  bf16x8 af0, af1, af2, af3;

#define AL(t)                                                                  \
  {                                                                            \
    const float* p_ = pA + (size_t)(t)*32;                                     \
    xr0 = *(const f32x4*)(p_);                                                 \
    xr1 = *(const f32x4*)(p_ + 4);                                             \
    xr2 = *(const f32x4*)(p_ + 16 * (size_t)K);                                \
    xr3 = *(const f32x4*)(p_ + 16 * (size_t)K + 4);                            \
    xr4 = *(const f32x4*)(p_ + 32 * (size_t)K);                                \
    xr5 = *(const f32x4*)(p_ + 32 * (size_t)K + 4);                            \
    xr6 = *(const f32x4*)(p_ + 48 * (size_t)K);                                \
    xr7 = *(const f32x4*)(p_ + 48 * (size_t)K + 4);                            \
  }
#define CVT1(dst, ra, rb)                                                      \
  {                                                                            \
    bf16x8 v_;                                                                 \
    _Pragma("unroll") for (int j_ = 0; j_ < 4; ++j_) {                         \
      v_[j_] = (__bf16)(ra)[j_];                                               \
      v_[4 + j_] = (__bf16)(rb)[j_];                                           \
    }                                                                          \
    dst = v_;                                                                  \
  }
#define ACVT                                                                   \
  CVT1(af0, xr0, xr1);                                                         \
  CVT1(af1, xr2, xr3);                                                         \
  CVT1(af2, xr4, xr5);                                                         \
  CVT1(af3, xr6, xr7);
#define BG2(t, NS)                                                             \
  {                                                                            \
    GLOAD_LDS16(pBg + (size_t)(t)*32, &Bs[NS][(wid * 32) * 32]);               \
    GLOAD_LDS16(pBg + 16 * (size_t)K + (size_t)(t)*32,                         \
                &Bs[NS][(wid * 32 + 16) * 32]);                                \
  }

  // Window t: [issue A(t+1) (oldest) + B(t+1)->NS] ; 8 b128 B reads from S;
  // lgkm drain; 32 MFMA (af = A(t) cvt'd last window); cvt A(t+1) (compiler
  // auto-waits vmcnt(2): A done, B still in flight); vmcnt(0) drains B
  // (issued a whole MFMA phase ago); barrier; flip. MODE 2 = last window.
#define ITER(S, NS, t, MODE)                                                   \
  {                                                                            \
    if (MODE == 0) {                                                           \
      AL((t) + 1);                                                             \
      SB0;                                                                     \
      BG2((t) + 1, NS);                                                        \
      SB0;                                                                     \
    }                                                                          \
    bf16x8 b_[8];                                                              \
    _Pragma("unroll") for (int j_ = 0; j_ < 8; ++j_) b_[j_] =                  \
        *(const bf16x8*)&Bs[S][boff + j_ * 512];                               \
    LGKM0;                                                                     \
    SB0;                                                                       \
    __builtin_amdgcn_s_setprio(1);                                             \
    _Pragma("unroll") for (int nj_ = 0; nj_ < 8; ++nj_) {                      \
      acc[0][nj_] = __builtin_amdgcn_mfma_f32_16x16x32_bf16(                   \
          af0, b_[nj_], acc[0][nj_], 0, 0, 0);                                 \
      acc[1][nj_] = __builtin_amdgcn_mfma_f32_16x16x32_bf16(                   \
          af1, b_[nj_], acc[1][nj_], 0, 0, 0);                                 \
      acc[2][nj_] = __builtin_amdgcn_mfma_f32_16x16x32_bf16(                   \
          af2, b_[nj_], acc[2][nj_], 0, 0, 0);                                 \
      acc[3][nj_] = __builtin_amdgcn_mfma_f32_16x16x32_bf16(                   \
          af3, b_[nj_], acc[3][nj_], 0, 0, 0);                                 \
    }                                                                          \
    __builtin_amdgcn_s_setprio(0);                                             \
    SB0;                                                                       \
    if (MODE == 0) {                                                           \
      ACVT;                                                                    \
      SB0;                                                                     \
      VMC(0);                                                                  \
      BARRIER;                                                                 \
    }                                                                          \
  }

  // ---- prologue: stage tile 0 (A -> regs -> af, B -> slot0) ----
  AL(0);
  SB0;
  BG2(0, 0);
  SB0;
  ACVT;  // compiler auto-waits the 8 A loads (vmcnt(2)), leaves B in flight
  VMC(0);
  BARRIER;

  // ---- main loop: 64 windows ----
  for (int t = 0; t < NT - 2; t += 2) {
    ITER(0, 1, t, 0);
    ITER(1, 0, t + 1, 0);
  }
  ITER(0, 1, NT - 2, 0);  // t=62: stages window 63 -> slot1
  ITER(1, 0, NT - 1, 2);  // t=63: no stage, no barrier

  // ---- epilogue 1: fused column partial stats from live accumulators ----
  // C/D layout: col = wc*128 + nj*16 + frow, row = wr*64 + mi*16 + fcb*4 + j
#pragma unroll
  for (int nj = 0; nj < 8; ++nj) {
    float s = 0.f, q = 0.f;
#pragma unroll
    for (int mi = 0; mi < 4; ++mi)
#pragma unroll
      for (int j = 0; j < 4; ++j) {
        float v = acc[mi][nj][j];
        s += v;
        q += v * v;
      }
    s += __shfl_xor(s, 16);  // reduce over fcb (lane bits 4-5)
    s += __shfl_xor(s, 32);
    q += __shfl_xor(q, 16);
    q += __shfl_xor(q, 32);
    if (fcb == 0) {
      redsum[wr][wc * 128 + nj * 16 + frow] = s;
      redsq[wr][wc * 128 + nj * 16 + frow] = q;
    }
  }
  __syncthreads();
  if (tid < BN) {
    psum[(size_t)tm * N + n0 + tid] =
        redsum[0][tid] + redsum[1][tid] + redsum[2][tid] + redsum[3][tid];
    psq[(size_t)tm * N + n0 + tid] =
        redsq[0][tid] + redsq[1][tid] + redsq[2][tid] + redsq[3][tid];
  }

  // ---- epilogue 2: store Y fp32 (raw pre-BN accumulators) ----
#pragma unroll
  for (int mi = 0; mi < 4; ++mi) {
    const size_t r0 = m0 + wr * 64 + mi * 16 + fcb * 4;
#pragma unroll
    for (int nj = 0; nj < 8; ++nj) {
      float* yp = Y + r0 * N + n0 + wc * 128 + nj * 16 + frow;
#pragma unroll
      for (int j = 0; j < 4; ++j) yp[(size_t)j * N] = acc[mi][nj][j];
    }
  }
}

// ---- finalize BN stats -> per-column scale/shift ----
__global__ __launch_bounds__(256) void bnstats_kernel(
    const float* __restrict__ psum, const float* __restrict__ psq,
    const float* __restrict__ gamma, const float* __restrict__ beta,
    float* __restrict__ scale, float* __restrict__ shift) {
  const int c = blockIdx.x * 256 + threadIdx.x;
  float s = 0.f, q = 0.f;
  for (int i = 0; i < TM2; ++i) {
    s += psum[i * N + c];
    q += psq[i * N + c];
  }
  const float mean = s * (1.f / (float)M);
  const float var = q * (1.f / (float)M) - mean * mean;
  const float inv = rsqrtf(var + BN_EPS);
  const float sc = gamma[c] * inv;
  scale[c] = sc;
  shift[c] = beta[c] - mean * sc;
}

// ---- apply BN in place on fp32 Y (= d_out), 4 floats / thread ----
__global__ __launch_bounds__(256) void bnapply_kernel(
    float* __restrict__ Y, const float* __restrict__ scale,
    const float* __restrict__ shift) {
  const size_t i = (size_t)blockIdx.x * 256 + threadIdx.x;
  f32x4 y = ((const f32x4*)Y)[i];
  const int c = (int)((i * 4) & (N - 1));
  f32x4 sc = *(const f32x4*)&scale[c];
  f32x4 sh = *(const f32x4*)&shift[c];
  ((f32x4*)Y)[i] = y * sc + sh;
}

extern "C" void kernel_launch(void* const* d_in, const int* in_sizes, int n_in,
                              void* d_out, int out_size, void* d_ws,
                              size_t ws_size, hipStream_t stream) {
  const float* x = (const float*)d_in[0];
  const float* w = (const float*)d_in[1];
  // d_in[2] = bias: a per-column constant shift cancels exactly in BatchNorm
  const float* gamma = (const float*)d_in[3];
  const float* beta = (const float*)d_in[4];
  float* Y = (float*)d_out;  // y staged here fp32, normalized in place

  char* ws = (char*)d_ws;
  uint4v* wb = (uint4v*)ws;  // 4 MiB
  float* psum = (float*)(ws + (size_t)N * K * 2);
  float* psq = psum + (size_t)TM2 * N;  // 256 KiB each
  float* scale = psq + (size_t)TM2 * N;
  float* shift = scale + N;

  binw_kernel<<<(N * K / 8) / 256, 256, 0, stream>>>(w, wb);
  gemm_bin_kernel<<<(M / BM) * (N / BN), 512, 0, stream>>>(
      x, (const unsigned short*)wb, Y, psum, psq);
  bnstats_kernel<<<N / 256, 256, 0, stream>>>(psum, psq, gamma, beta, scale,
                                              shift);
  bnapply_kernel<<<(M * N / 4) / 256, 256, 0, stream>>>(Y, scale, shift);
}

// Round 7
// 116.774 us; speedup vs baseline: 1.7879x; 1.7879x over previous
//
#include <hip/hip_runtime.h>
#include <hip/hip_bf16.h>

typedef __attribute__((ext_vector_type(4))) float f32x4;
typedef __attribute__((ext_vector_type(8))) __bf16 bf16x8;
typedef __attribute__((ext_vector_type(4))) unsigned int uint4v;

constexpr int M = 16384;
constexpr int N = 1024;
constexpr int K = 2048;
constexpr int BM = 256, BN = 256, BK = 64;  // m201-style 8-phase template
constexpr int NKT = K / BK;                 // 32 K-tiles
constexpr float BN_EPS = 1e-5f;
constexpr int TM2 = M / BM;  // 64 row-tiles (psum partials)

// async 16B global -> LDS (lds dest must be wave-uniform; HW adds lane*16)
#define GLOAD_LDS16(g, l)                                                      \
  __builtin_amdgcn_global_load_lds(                                            \
      (const __attribute__((address_space(1))) void*)(g),                      \
      (__attribute__((address_space(3))) void*)(l), 16, 0, 0)

#define SB0 __builtin_amdgcn_sched_barrier(0)
#define BARRIER __builtin_amdgcn_s_barrier()
#define LGKM0 asm volatile("s_waitcnt lgkmcnt(0)" ::: "memory")
#define VMC(n) asm volatile("s_waitcnt vmcnt(" #n ")" ::: "memory")

__device__ __forceinline__ unsigned sgnbf(float f) {
  return (f >= 0.f) ? 0x3F80u : 0xBF80u;
}
__global__ __launch_bounds__(256) void binw_kernel(
    const float* __restrict__ w, uint4v* __restrict__ wb) {
  size_t i = (size_t)blockIdx.x * 256 + threadIdx.x;
  const f32x4* win = (const f32x4*)w;
  f32x4 v0 = win[i * 2];
  f32x4 v1 = win[i * 2 + 1];
  uint4v o;
  o.x = sgnbf(v0[0]) | (sgnbf(v0[1]) << 16);
  o.y = sgnbf(v0[2]) | (sgnbf(v0[3]) << 16);
  o.z = sgnbf(v1[0]) | (sgnbf(v1[1]) << 16);
  o.w = sgnbf(v1[2]) | (sgnbf(v1[3]) << 16);
  wb[i] = o;
}

// ---- bf16 GEMM: faithful m201 8-phase port, 256^2 tile, BK=64 ----
// 512 thr = 8 waves (2M x 4N), wave tile 128x64, acc[8][4], 2-slot LDS.
// K-tile stored as TWO 32-k planes of 64B rows (the R0/R4/R6-measured
// 0-conflict atom: row = 32 ushorts, chunk XOR (row>>1)&3 involution) —
// never a 128B row (R3's 2.1M-conflict mistake).
// Per K-tile: 4 phases x {ds-read frags; stage issue; barrier; lgkm0+SB0;
// setprio(1); 16 MFMA; setprio(0); barrier}. Staging discipline (counted,
// never early-drained): B(t+1) DMA issued at ph0 (ks0) / ph1 (ks1), A(t+1)
// fp32 reg-loads issued at ph1 AFTER the B's; A drained at ph3 by the
// cvt's compiler-derived waitcnt (vmcnt->0 exactly drains the older B
// DMAs too), then ds_write + lgkm0 + trailing barrier publishes the slot.
// A ds_write uses R0's verified wave pattern (16 consecutive rows x 4
// chunks = contiguous 1KB per wave-instr, 0 conflicts measured).
__global__ __launch_bounds__(512, 2) void gemm_bin_kernel(
    const float* __restrict__ Af, const unsigned short* __restrict__ B,
    float* __restrict__ Y, float* __restrict__ psum, float* __restrict__ psq) {
  __shared__ unsigned short Asd[2][2][8192];  // [slot][plane][row*32+chunk*8]
  __shared__ unsigned short Bsd[2][2][8192];  // 64 KiB each
  __shared__ float redsum[2][256];            // 2 KiB
  __shared__ float redsq[2][256];             // 2 KiB

  const int tid = threadIdx.x;
  const int wid = tid >> 6;
  const int lane = tid & 63;
  const int wr = wid >> 2, wc = wid & 3;  // 2x4 wave grid, wave owns 128x64

  // T1: XCD swizzle (grid 256, %8==0): XCD owns contiguous tm range.
  const int bid = blockIdx.x;
  const int swz = (bid & 7) * 32 + (bid >> 3);
  const int tm = swz >> 2, tn = swz & 3;
  const size_t m0 = (size_t)tm * BM, n0 = (size_t)tn * BN;

  const int frow = lane & 15;  // fragment row/col within 16x16
  const int fcb = lane >> 4;   // k chunk 0..3
  const int swq = (frow >> 1) & 3;
  // frag read offsets (ushort idx within a plane); +mi*512 / +nj*512
  const int aoff = (wr * 128 + frow) * 32 + (fcb ^ swq) * 8;
  const int boff = (wc * 64 + frow) * 32 + (fcb ^ swq) * 8;

  // B staging (gload_lds): wave stages rows [wid*32,+32) per plane as two
  // 16-row units. lane: row += lane>>2, lds chunk = lane&3, global chunk =
  // (lane&3)^((lane>>3)&3)  (row>>1)&3 reduces to (lane>>3)&3 here).
  const unsigned short* pBg =
      B + (n0 + wid * 32 + (lane >> 2)) * (size_t)K +
      (((lane & 3) ^ ((lane >> 3) & 3)) * 8);

  // A staging (reg+cvt): wave covers rows [wid*32,+32), both planes, as 4
  // units k=0..3: rows wid*32+(k&1)*16+(lane>>2), plane k>>1, lds chunk
  // lane&3 (global chunk XOR'd). Same 16-row x 4-chunk contiguous-1KB
  // write pattern as R0 (measured 0 conflicts).
  const size_t aRowK = (m0 + wid * 32 + (lane >> 2)) * (size_t)K;
  const float* pAg = Af + aRowK + (((lane & 3) ^ ((lane >> 3) & 3)) * 8);
  const int awb = (wid * 32 + (lane >> 2)) * 32 + (lane & 3) * 8;

  f32x4 acc[8][4];
#pragma unroll
  for (int mi = 0; mi < 8; ++mi)
#pragma unroll
    for (int nj = 0; nj < 4; ++nj)
#pragma unroll
      for (int j = 0; j < 4; ++j) acc[mi][nj][j] = 0.f;

  f32x4 xq0, xq1, xq2, xq3, xq4, xq5, xq6, xq7;

#define BG(g, ks, t, NS)                                                       \
  GLOAD_LDS16(pBg + (size_t)(g)*16 * K + (size_t)(t)*64 + (ks)*32,             \
              &Bsd[NS][ks][(wid * 32 + (g)*16) * 32])

  // k-unit (k&1)=row-half, (k>>1)=plane: global addr + (k&1)*16*K + (k>>1)*32
#define ALOAD(t)                                                               \
  {                                                                            \
    const float* p_ = pAg + (size_t)(t)*64;                                    \
    xq0 = *(const f32x4*)(p_);                                                 \
    xq1 = *(const f32x4*)(p_ + 4);                                             \
    xq2 = *(const f32x4*)(p_ + 16 * (size_t)K);                                \
    xq3 = *(const f32x4*)(p_ + 16 * (size_t)K + 4);                            \
    xq4 = *(const f32x4*)(p_ + 32);                                            \
    xq5 = *(const f32x4*)(p_ + 36);                                            \
    xq6 = *(const f32x4*)(p_ + 16 * (size_t)K + 32);                           \
    xq7 = *(const f32x4*)(p_ + 16 * (size_t)K + 36);                           \
  }
#define CVW(dst, ra, rb)                                                       \
  {                                                                            \
    bf16x8 v_;                                                                 \
    _Pragma("unroll") for (int j_ = 0; j_ < 4; ++j_) {                         \
      v_[j_] = (__bf16)(ra)[j_];                                               \
      v_[4 + j_] = (__bf16)(rb)[j_];                                           \
    }                                                                          \
    *(bf16x8*)(dst) = v_;                                                      \
  }
#define AWRITE(NS)                                                             \
  {                                                                            \
    CVW(&Asd[NS][0][awb], xq0, xq1);                                           \
    CVW(&Asd[NS][0][awb + 512], xq2, xq3);                                     \
    CVW(&Asd[NS][1][awb], xq4, xq5);                                           \
    CVW(&Asd[NS][1][awb + 512], xq6, xq7);                                     \
  }

#define MQ(MB)                                                                 \
  LGKM0;                                                                       \
  SB0;                                                                         \
  __builtin_amdgcn_s_setprio(1);                                               \
  _Pragma("unroll") for (int i_ = 0; i_ < 4; ++i_)                             \
      _Pragma("unroll") for (int j_ = 0; j_ < 4; ++j_) acc[(MB) + i_][j_] =    \
          __builtin_amdgcn_mfma_f32_16x16x32_bf16(aq[i_], bq[j_],              \
                                                  acc[(MB) + i_][j_], 0, 0,    \
                                                  0);                          \
  __builtin_amdgcn_s_setprio(0);                                               \
  SB0;

  // TILE(S,NS,t,STG): compute tile t from slot S; stage tile t+1 into NS.
#define TILE(S, NS, t, STG)                                                    \
  {                                                                            \
    bf16x8 aq[4], bq[4];                                                       \
    /* ph0: B ks0 + A ks0 mi0-3; issue B(t+1) ks0 DMA */                       \
    _Pragma("unroll") for (int j_ = 0; j_ < 4; ++j_) bq[j_] =                  \
        *(const bf16x8*)&Bsd[S][0][boff + j_ * 512];                           \
    _Pragma("unroll") for (int i_ = 0; i_ < 4; ++i_) aq[i_] =                  \
        *(const bf16x8*)&Asd[S][0][aoff + i_ * 512];                           \
    SB0;                                                                       \
    if (STG) {                                                                 \
      BG(0, 0, (t) + 1, NS);                                                   \
      BG(1, 0, (t) + 1, NS);                                                   \
      SB0;                                                                     \
    }                                                                          \
    BARRIER;                                                                   \
    MQ(0);                                                                     \
    BARRIER;                                                                   \
    /* ph1: A ks0 mi4-7 (bq reused); issue B(t+1) ks1 DMA then A(t+1) */       \
    _Pragma("unroll") for (int i_ = 0; i_ < 4; ++i_) aq[i_] =                  \
        *(const bf16x8*)&Asd[S][0][aoff + (4 + i_) * 512];                     \
    SB0;                                                                       \
    if (STG) {                                                                 \
      BG(0, 1, (t) + 1, NS);                                                   \
      BG(1, 1, (t) + 1, NS);                                                   \
      SB0;                                                                     \
      ALOAD((t) + 1);                                                          \
      SB0;                                                                     \
    }                                                                          \
    BARRIER;                                                                   \
    MQ(4);                                                                     \
    BARRIER;                                                                   \
    /* ph2: B ks1 + A ks1 mi0-3 */                                             \
    _Pragma("unroll") for (int j_ = 0; j_ < 4; ++j_) bq[j_] =                  \
        *(const bf16x8*)&Bsd[S][1][boff + j_ * 512];                           \
    _Pragma("unroll") for (int i_ = 0; i_ < 4; ++i_) aq[i_] =                  \
        *(const bf16x8*)&Asd[S][1][aoff + i_ * 512];                           \
    SB0;                                                                       \
    BARRIER;                                                                   \
    MQ(0);                                                                     \
    BARRIER;                                                                   \
    /* ph3: A ks1 mi4-7; cvt A(t+1) (auto-wait drains A + older B DMAs), */    \
    /* ds_write -> NS; lgkm0 inside MQ + trailing barrier publish slot */      \
    _Pragma("unroll") for (int i_ = 0; i_ < 4; ++i_) aq[i_] =                  \
        *(const bf16x8*)&Asd[S][1][aoff + (4 + i_) * 512];                     \
    SB0;                                                                       \
    if (STG) {                                                                 \
      AWRITE(NS);                                                              \
      SB0;                                                                     \
    }                                                                          \
    BARRIER;                                                                   \
    MQ(4);                                                                     \
    if (STG) BARRIER;                                                          \
  }

  // ---- prologue: stage tile 0 -> slot 0 ----
  BG(0, 0, 0, 0);
  BG(1, 0, 0, 0);
  BG(0, 1, 0, 0);
  BG(1, 1, 0, 0);
  SB0;
  ALOAD(0);
  SB0;
  AWRITE(0);  // cvt auto-waits the 8 A loads -> vmcnt 0, drains the 4 B DMAs
  LGKM0;
  BARRIER;

  // ---- main loop: 32 K-tiles ----
  for (int t = 0; t < NKT - 2; t += 2) {
    TILE(0, 1, t, 1);
    TILE(1, 0, t + 1, 1);
  }
  TILE(0, 1, NKT - 2, 1);  // t=30: stages tile 31 -> slot1
  TILE(1, 0, NKT - 1, 0);  // t=31: no stage

  // ---- epilogue 1: fused column partial stats from live accumulators ----
  // C/D layout: col = wc*64 + nj*16 + frow, row = wr*128 + mi*16 + fcb*4 + j
#pragma unroll
  for (int nj = 0; nj < 4; ++nj) {
    float s = 0.f, q = 0.f;
#pragma unroll
    for (int mi = 0; mi < 8; ++mi)
#pragma unroll
      for (int j = 0; j < 4; ++j) {
        float v = acc[mi][nj][j];
        s += v;
        q += v * v;
      }
    s += __shfl_xor(s, 16);  // reduce over fcb (lane bits 4-5)
    s += __shfl_xor(s, 32);
    q += __shfl_xor(q, 16);
    q += __shfl_xor(q, 32);
    if (fcb == 0) {
      redsum[wr][wc * 64 + nj * 16 + frow] = s;
      redsq[wr][wc * 64 + nj * 16 + frow] = q;
    }
  }
  __syncthreads();
  if (tid < BN) {
    psum[(size_t)tm * N + n0 + tid] = redsum[0][tid] + redsum[1][tid];
    psq[(size_t)tm * N + n0 + tid] = redsq[0][tid] + redsq[1][tid];
  }

  // ---- epilogue 2: store Y fp32 (raw pre-BN accumulators) ----
#pragma unroll
  for (int mi = 0; mi < 8; ++mi) {
    const size_t r0 = m0 + wr * 128 + mi * 16 + fcb * 4;
#pragma unroll
    for (int nj = 0; nj < 4; ++nj) {
      float* yp = Y + r0 * N + n0 + wc * 64 + nj * 16 + frow;
#pragma unroll
      for (int j = 0; j < 4; ++j) yp[(size_t)j * N] = acc[mi][nj][j];
    }
  }
}

// ---- finalize BN stats -> per-column scale/shift ----
__global__ __launch_bounds__(256) void bnstats_kernel(
    const float* __restrict__ psum, const float* __restrict__ psq,
    const float* __restrict__ gamma, const float* __restrict__ beta,
    float* __restrict__ scale, float* __restrict__ shift) {
  const int c = blockIdx.x * 256 + threadIdx.x;
  float s = 0.f, q = 0.f;
  for (int i = 0; i < TM2; ++i) {
    s += psum[i * N + c];
    q += psq[i * N + c];
  }
  const float mean = s * (1.f / (float)M);
  const float var = q * (1.f / (float)M) - mean * mean;
  const float inv = rsqrtf(var + BN_EPS);
  const float sc = gamma[c] * inv;
  scale[c] = sc;
  shift[c] = beta[c] - mean * sc;
}

// ---- apply BN in place on fp32 Y (= d_out), 4 floats / thread ----
__global__ __launch_bounds__(256) void bnapply_kernel(
    float* __restrict__ Y, const float* __restrict__ scale,
    const float* __restrict__ shift) {
  const size_t i = (size_t)blockIdx.x * 256 + threadIdx.x;
  f32x4 y = ((const f32x4*)Y)[i];
  const int c = (int)((i * 4) & (N - 1));
  f32x4 sc = *(const f32x4*)&scale[c];
  f32x4 sh = *(const f32x4*)&shift[c];
  ((f32x4*)Y)[i] = y * sc + sh;
}

extern "C" void kernel_launch(void* const* d_in, const int* in_sizes, int n_in,
                              void* d_out, int out_size, void* d_ws,
                              size_t ws_size, hipStream_t stream) {
  const float* x = (const float*)d_in[0];
  const float* w = (const float*)d_in[1];
  // d_in[2] = bias: a per-column constant shift cancels exactly in BatchNorm
  const float* gamma = (const float*)d_in[3];
  const float* beta = (const float*)d_in[4];
  float* Y = (float*)d_out;  // y staged here fp32, normalized in place

  char* ws = (char*)d_ws;
  uint4v* wb = (uint4v*)ws;  // 4 MiB
  float* psum = (float*)(ws + (size_t)N * K * 2);
  float* psq = psum + (size_t)TM2 * N;  // 256 KiB each
  float* scale = psq + (size_t)TM2 * N;
  float* shift = scale + N;

  binw_kernel<<<(N * K / 8) / 256, 256, 0, stream>>>(w, wb);
  gemm_bin_kernel<<<(M / BM) * (N / BN), 512, 0, stream>>>(
      x, (const unsigned short*)wb, Y, psum, psq);
  bnstats_kernel<<<N / 256, 256, 0, stream>>>(psum, psq, gamma, beta, scale,
                                              shift);
  bnapply_kernel<<<(M * N / 4) / 256, 256, 0, stream>>>(Y, scale, shift);
}